// Round 13
// baseline (495.899 us; speedup 1.0000x reference)
//
#include <hip/hip_runtime.h>
#include <math.h>

static constexpr int BB  = 16;
static constexpr int NN  = 2048;
static constexpr int CC  = 384;
static constexpr int KCL = 512;
static constexpr float RSQC = 0.051031036307982884f; // 1/sqrt(384)

typedef short  bf16x8 __attribute__((ext_vector_type(8)));
typedef float  f32x4  __attribute__((ext_vector_type(4)));

__device__ __forceinline__ unsigned short f2b(float v) {
    unsigned u = __float_as_uint(v);
    unsigned r = (u + 0x7FFFu + ((u >> 16) & 1u)) >> 16; // RNE
    return (unsigned short)r;
}
__device__ __forceinline__ float b2f(unsigned short b) {
    return __uint_as_float(((unsigned)b) << 16);
}
__device__ __forceinline__ void gload16(const void* g, void* l) {
    __builtin_amdgcn_global_load_lds(
        (const __attribute__((address_space(1))) void*)g,
        (__attribute__((address_space(3))) void*)l, 16, 0, 0);
}
__device__ __forceinline__ void ins5(float* t5, float v) {
    if (v < t5[4]) {
        t5[4] = v;
        #pragma unroll
        for (int q = 4; q > 0; --q) {
            if (t5[q] < t5[q - 1]) { float tmp = t5[q - 1]; t5[q - 1] = t5[q]; t5[q] = tmp; }
        }
    }
}

// ---------------- kernel 0 (fused, vectorized): |x|^2, weight, hi/lo split ----------------
__global__ __launch_bounds__(256) void k_prep(
    const float* __restrict__ x, const float* __restrict__ sw,
    const float* __restrict__ sb, float* __restrict__ sq, float* __restrict__ tw,
    unsigned short* __restrict__ Xh, unsigned short* __restrict__ Xl,
    unsigned* __restrict__ dmaxraw)
{
    if (blockIdx.x == 0 && threadIdx.x < 64) dmaxraw[threadIdx.x] = 0u;
    int row  = blockIdx.x * 4 + (threadIdx.x >> 6);
    int lane = threadIdx.x & 63;
    const float* xr = x + (size_t)row * CC;
    float s2 = 0.f, sd = 0.f;
    if (lane < 48) {                       // 48 chunks of 8 = 384
        const float* p  = xr + lane * 8;
        const float* pw = sw + lane * 8;
        float4 a0 = *(const float4*)(p);
        float4 a1 = *(const float4*)(p + 4);
        float4 w0 = *(const float4*)(pw);
        float4 w1 = *(const float4*)(pw + 4);
        float vv[8] = {a0.x,a0.y,a0.z,a0.w,a1.x,a1.y,a1.z,a1.w};
        float ww[8] = {w0.x,w0.y,w0.z,w0.w,w1.x,w1.y,w1.z,w1.w};
        unsigned short h[8], lo[8];
        #pragma unroll
        for (int e = 0; e < 8; ++e) {
            s2 += vv[e] * vv[e];
            sd += vv[e] * ww[e];
            h[e]  = f2b(vv[e]);
            lo[e] = f2b(vv[e] - b2f(h[e]));
        }
        *(bf16x8*)(Xh + (size_t)row * CC + lane * 8) = *(bf16x8*)h;
        *(bf16x8*)(Xl + (size_t)row * CC + lane * 8) = *(bf16x8*)lo;
    }
    #pragma unroll
    for (int o = 32; o > 0; o >>= 1) {
        s2 += __shfl_down(s2, o);
        sd += __shfl_down(sd, o);
    }
    if (lane == 0) {
        sq[row] = s2;
        tw[row] = expf(sd + sb[0]);
    }
}

// ---------------- fallback: per-row |x|^2 and token weight ----------------
__global__ __launch_bounds__(256) void k_rowstats(
    const float* __restrict__ x, const float* __restrict__ sw,
    const float* __restrict__ sb, float* __restrict__ sq, float* __restrict__ tw)
{
    int row  = blockIdx.x * 4 + (threadIdx.x >> 6);
    int lane = threadIdx.x & 63;
    const float* xr = x + (size_t)row * CC;
    float s2 = 0.f, sd = 0.f;
    for (int c = lane; c < CC; c += 64) {
        float v = xr[c];
        s2 += v * v;
        sd += v * sw[c];
    }
    #pragma unroll
    for (int o = 32; o > 0; o >>= 1) {
        s2 += __shfl_down(s2, o);
        sd += __shfl_down(sd, o);
    }
    if (lane == 0) {
        sq[row] = s2;
        tw[row] = expf(sd + sb[0]);
    }
}

// ======================= PATH A: stored-D (fp32) pipeline =======================

// Symmetric split-bf16 MFMA GEMM over upper-triangle 128x128 tiles.
// Linear tile order (NO swizzle: keeps last-written D tiles hot for the tail).
__global__ __launch_bounds__(256) void k_gemm_sym(
    const unsigned short* __restrict__ Xh, const unsigned short* __restrict__ Xl,
    const float* __restrict__ sq, float* __restrict__ D, int b0)
{
    const int b = b0 + blockIdx.z;
    int q = blockIdx.x;
    int ti = 0;
    while (q >= (16 - ti)) { q -= (16 - ti); ++ti; }
    const int tj = ti + q;
    const int i0 = ti * 128, j0 = tj * 128;

    const unsigned short* Xhb = Xh + (size_t)b * NN * CC;
    const unsigned short* Xlb = Xl + (size_t)b * NN * CC;
    const float* sqb = sq + b * NN;
    float* Db = D + (size_t)blockIdx.z * NN * NN;

    __shared__ union {
        unsigned short u16[4][128][32]; // [plane][row][k-slot*8]
        float tr[64][129];              // transpose buffer (epilogue only)
    } sm;

    const int t  = threadIdx.x;
    const int w  = t >> 6;
    const int l  = t & 63;
    const int wr = w >> 1, wc = w & 1;
    const int lt = l & 15, sl = l >> 4;

    f32x4 acc[4][4];
    #pragma unroll
    for (int fr = 0; fr < 4; ++fr)
        #pragma unroll
        for (int fc = 0; fc < 4; ++fc) acc[fr][fc] = (f32x4)0.0f;

    for (int kc = 0; kc < CC; kc += 32) {
        #pragma unroll
        for (int p = 0; p < 4; ++p) {
            const unsigned short* src = (p == 0) ? Xhb : (p == 1) ? Xlb
                                      : (p == 2) ? Xhb : Xlb;
            const int base0 = (p < 2) ? i0 : j0;
            #pragma unroll
            for (int u = 0; u < 2; ++u) {
                int seg = w * 2 + u;
                int r   = seg * 16 + (l >> 2);
                int s   = (l & 3) ^ ((r >> 1) & 3);
                gload16(src + (size_t)(base0 + r) * CC + kc + s * 8,
                        &sm.u16[p][seg * 16][0]);
            }
        }
        __syncthreads();

        bf16x8 fah[4], fal[4], fbh[4], fbl[4];
        #pragma unroll
        for (int fr = 0; fr < 4; ++fr) {
            int ra = wr * 64 + fr * 16 + lt;
            int sa = (sl ^ ((ra >> 1) & 3)) * 8;
            fah[fr] = *(const bf16x8*)&sm.u16[0][ra][sa];
            fal[fr] = *(const bf16x8*)&sm.u16[1][ra][sa];
        }
        #pragma unroll
        for (int fc = 0; fc < 4; ++fc) {
            int rb = wc * 64 + fc * 16 + lt;
            int sb_ = (sl ^ ((rb >> 1) & 3)) * 8;
            fbh[fc] = *(const bf16x8*)&sm.u16[2][rb][sb_];
            fbl[fc] = *(const bf16x8*)&sm.u16[3][rb][sb_];
        }
        #pragma unroll
        for (int fr = 0; fr < 4; ++fr)
            #pragma unroll
            for (int fc = 0; fc < 4; ++fc) {
                acc[fr][fc] = __builtin_amdgcn_mfma_f32_16x16x32_bf16(
                    fah[fr], fbh[fc], acc[fr][fc], 0, 0, 0);
                acc[fr][fc] = __builtin_amdgcn_mfma_f32_16x16x32_bf16(
                    fah[fr], fbl[fc], acc[fr][fc], 0, 0, 0);
                acc[fr][fc] = __builtin_amdgcn_mfma_f32_16x16x32_bf16(
                    fal[fr], fbh[fc], acc[fr][fc], 0, 0, 0);
            }
        __syncthreads();
    }

    float sqr[4][4], sqc[4];
    #pragma unroll
    for (int fr = 0; fr < 4; ++fr)
        #pragma unroll
        for (int reg = 0; reg < 4; ++reg)
            sqr[fr][reg] = sqb[i0 + wr * 64 + fr * 16 + sl * 4 + reg];
    #pragma unroll
    for (int fc = 0; fc < 4; ++fc)
        sqc[fc] = sqb[j0 + wc * 64 + fc * 16 + lt];

    #pragma unroll
    for (int fr = 0; fr < 4; ++fr)
        #pragma unroll
        for (int fc = 0; fc < 4; ++fc)
            #pragma unroll
            for (int reg = 0; reg < 4; ++reg) {
                int row = i0 + wr * 64 + fr * 16 + sl * 4 + reg;
                int col = j0 + wc * 64 + fc * 16 + lt;
                float d2 = fmaxf(sqr[fr][reg] + sqc[fc] - 2.0f * acc[fr][fc][reg], 0.0f);
                Db[(size_t)row * NN + col] = d2;
            }

    if (ti != tj) {
        #pragma unroll
        for (int h = 0; h < 2; ++h) {
            __syncthreads();
            if (wr == h) {
                #pragma unroll
                for (int fr = 0; fr < 4; ++fr)
                    #pragma unroll
                    for (int fc = 0; fc < 4; ++fc)
                        #pragma unroll
                        for (int reg = 0; reg < 4; ++reg) {
                            int rl = fr * 16 + sl * 4 + reg;
                            int cl = wc * 64 + fc * 16 + lt;
                            float d2 = fmaxf(sqr[fr][reg] + sqc[fc]
                                             - 2.0f * acc[fr][fc][reg], 0.0f);
                            sm.tr[rl][cl] = d2;
                        }
            }
            __syncthreads();
            for (int idx = t; idx < 128 * 64; idx += 256) {
                int c  = idx >> 6;
                int rl = idx & 63;
                Db[(size_t)(j0 + c) * NN + i0 + h * 64 + rl] = sm.tr[rl][c];
            }
        }
    }
}

// density from stored D: one wave per row (top5 d2 + max d2); per-batch d2max
// folded in via deterministic bitwise atomicMax.
__global__ __launch_bounds__(256) void k_density2(
    const float* __restrict__ D, const float* __restrict__ noise,
    float* __restrict__ dens, unsigned* __restrict__ dmaxraw)
{
    int gid  = blockIdx.x * 4 + (threadIdx.x >> 6);
    int lane = threadIdx.x & 63;
    const float* row = D + (size_t)gid * NN;
    float t5[5] = {1e30f, 1e30f, 1e30f, 1e30f, 1e30f};
    float mx = 0.f;
    #pragma unroll
    for (int it = 0; it < 8; ++it) {
        float4 v = ((const float4*)row)[it * 64 + lane];
        mx = fmaxf(mx, fmaxf(fmaxf(v.x, v.y), fmaxf(v.z, v.w)));
        ins5(t5, v.x); ins5(t5, v.y); ins5(t5, v.z); ins5(t5, v.w);
    }
    #pragma unroll
    for (int o = 1; o < 64; o <<= 1) {
        float b0 = __shfl_xor(t5[0], o), b1 = __shfl_xor(t5[1], o);
        float b2 = __shfl_xor(t5[2], o), b3 = __shfl_xor(t5[3], o);
        float b4 = __shfl_xor(t5[4], o);
        mx = fmaxf(mx, __shfl_xor(mx, o));
        ins5(t5, b0); ins5(t5, b1); ins5(t5, b2); ins5(t5, b3); ins5(t5, b4);
    }
    __shared__ float red[4];
    if (lane == 0) {
        float m2 = (t5[0] + t5[1] + t5[2] + t5[3] + t5[4]) * (1.0f / (5.0f * CC));
        dens[gid] = expf(-m2) + noise[gid] * 1e-6f;
        red[threadIdx.x >> 6] = mx;
    }
    __syncthreads();
    if (threadIdx.x == 0) {
        float m = fmaxf(fmaxf(red[0], red[1]), fmaxf(red[2], red[3]));
        int bl = (blockIdx.x * 4) >> 11;
        atomicMax(&dmaxraw[bl], __float_as_uint(m));
    }
}

// dmin from stored D (reads raw per-batch d2max)
__global__ __launch_bounds__(256) void k_dmin2(
    const float* __restrict__ D, const float* __restrict__ dens,
    const unsigned* __restrict__ dmaxraw, float* __restrict__ score)
{
    int gid  = blockIdx.x * 4 + (threadIdx.x >> 6);
    int lane = threadIdx.x & 63;
    int bl   = gid >> 11;
    const float* row = D + (size_t)gid * NN;
    const float* dn  = dens + (size_t)bl * NN;
    float di = dens[gid];
    float m = 1e30f;
    #pragma unroll
    for (int it = 0; it < 8; ++it) {
        float4 v  = ((const float4*)row)[it * 64 + lane];
        float4 dj = ((const float4*)dn)[it * 64 + lane];
        if (dj.x > di) m = fminf(m, v.x);
        if (dj.y > di) m = fminf(m, v.y);
        if (dj.z > di) m = fminf(m, v.z);
        if (dj.w > di) m = fminf(m, v.w);
    }
    #pragma unroll
    for (int o = 32; o > 0; o >>= 1) m = fminf(m, __shfl_down(m, o));
    if (lane == 0) {
        float dmv = sqrtf(__uint_as_float(dmaxraw[bl])) * RSQC;
        float dm = fminf(sqrtf(m) * RSQC, dmv);
        score[gid] = dm * di;
    }
}

// token -> nearest center from stored D, 4-way split-K; invc folds the override
__global__ __launch_bounds__(256) void k_assign2(
    const float* __restrict__ D, const int* __restrict__ idown,
    const int* __restrict__ invc, int* __restrict__ idxc)
{
    int bl = blockIdx.y;
    int tl = threadIdx.x & 63;
    int g  = threadIdx.x >> 6;
    int n  = blockIdx.x * 64 + tl;
    const float* Db = D + (size_t)bl * NN * NN;
    const int* idb  = idown + bl * KCL;
    float best = 1e30f; int bk = 0;
    for (int k = g * 128; k < (g + 1) * 128; ++k) {
        float v = Db[(size_t)idb[k] * NN + n];
        if (v < best) { best = v; bk = k; }
    }
    __shared__ float bvs[4][64];
    __shared__ int   bks[4][64];
    bvs[g][tl] = best; bks[g][tl] = bk;
    __syncthreads();
    if (threadIdx.x < 64) {
        float bv = bvs[0][threadIdx.x]; int bkk = bks[0][threadIdx.x];
        #pragma unroll
        for (int gg = 1; gg < 4; ++gg) {
            if (bvs[gg][threadIdx.x] < bv) { bv = bvs[gg][threadIdx.x]; bkk = bks[gg][threadIdx.x]; }
        }
        int nn = blockIdx.x * 64 + threadIdx.x;
        int iv = invc[bl * NN + nn];
        idxc[bl * NN + nn] = (iv >= 0) ? iv : bkk;
    }
}

// ======================= PATH B: recompute pipeline (fallback) =======================

__global__ __launch_bounds__(256) void k_density(
    const float* __restrict__ x, const float* __restrict__ sq,
    const float* __restrict__ noise, float* __restrict__ dens,
    float* __restrict__ rowmax)
{
    const int b  = blockIdx.y;
    const int i0 = blockIdx.x * 64;
    const float* xb  = x + (size_t)b * NN * CC;
    const float* sqb = sq + b * NN;
    __shared__ float As[16][64];
    __shared__ float Bs[16][64];
    __shared__ float mrg[64][16][5];
    __shared__ float mrgmax[64][16];
    const int t  = threadIdx.x;
    const int tx = t & 15, ty = t >> 4;
    const int lr = t >> 2, lk4 = (t & 3) * 4;

    float top[4][5];
    float rmax[4];
    float sqi[4];
    #pragma unroll
    for (int r = 0; r < 4; ++r) {
        sqi[r]  = sqb[i0 + ty * 4 + r];
        rmax[r] = 0.f;
        #pragma unroll
        for (int q = 0; q < 5; ++q) top[r][q] = 1e30f;
    }

    for (int j0 = 0; j0 < NN; j0 += 64) {
        float acc[4][4];
        #pragma unroll
        for (int r = 0; r < 4; ++r)
            #pragma unroll
            for (int s = 0; s < 4; ++s) acc[r][s] = 0.f;

        for (int k0 = 0; k0 < CC; k0 += 16) {
            float4 av = *(const float4*)(xb + (size_t)(i0 + lr) * CC + k0 + lk4);
            float4 bv = *(const float4*)(xb + (size_t)(j0 + lr) * CC + k0 + lk4);
            As[lk4 + 0][lr] = av.x; As[lk4 + 1][lr] = av.y;
            As[lk4 + 2][lr] = av.z; As[lk4 + 3][lr] = av.w;
            Bs[lk4 + 0][lr] = bv.x; Bs[lk4 + 1][lr] = bv.y;
            Bs[lk4 + 2][lr] = bv.z; Bs[lk4 + 3][lr] = bv.w;
            __syncthreads();
            #pragma unroll
            for (int kk = 0; kk < 16; ++kk) {
                float4 a4 = *(const float4*)&As[kk][ty * 4];
                float4 b4 = *(const float4*)&Bs[kk][tx * 4];
                float ar[4] = {a4.x, a4.y, a4.z, a4.w};
                float br[4] = {b4.x, b4.y, b4.z, b4.w};
                #pragma unroll
                for (int r = 0; r < 4; ++r)
                    #pragma unroll
                    for (int s = 0; s < 4; ++s)
                        acc[r][s] = fmaf(ar[r], br[s], acc[r][s]);
            }
            __syncthreads();
        }
        float sqj[4];
        #pragma unroll
        for (int s = 0; s < 4; ++s) sqj[s] = sqb[j0 + tx * 4 + s];
        #pragma unroll
        for (int r = 0; r < 4; ++r) {
            #pragma unroll
            for (int s = 0; s < 4; ++s) {
                float d2 = sqi[r] + sqj[s] - 2.0f * acc[r][s];
                float d  = sqrtf(fmaxf(d2, 0.0f)) * RSQC;
                rmax[r] = fmaxf(rmax[r], d);
                if (d < top[r][4]) {
                    top[r][4] = d;
                    #pragma unroll
                    for (int q = 4; q > 0; --q) {
                        if (top[r][q] < top[r][q - 1]) {
                            float tmp = top[r][q - 1];
                            top[r][q - 1] = top[r][q];
                            top[r][q] = tmp;
                        }
                    }
                }
            }
        }
    }
    #pragma unroll
    for (int r = 0; r < 4; ++r) {
        #pragma unroll
        for (int q = 0; q < 5; ++q) mrg[ty * 4 + r][tx][q] = top[r][q];
        mrgmax[ty * 4 + r][tx] = rmax[r];
    }
    __syncthreads();
    if (t < 64) {
        float t5[5] = {1e30f, 1e30f, 1e30f, 1e30f, 1e30f};
        float mx = 0.f;
        for (int c = 0; c < 16; ++c) {
            mx = fmaxf(mx, mrgmax[t][c]);
            #pragma unroll
            for (int q = 0; q < 5; ++q) ins5(t5, mrg[t][c][q]);
        }
        float m2 = (t5[0]*t5[0] + t5[1]*t5[1] + t5[2]*t5[2] +
                    t5[3]*t5[3] + t5[4]*t5[4]) / 5.0f;
        int i = i0 + t;
        dens[b * NN + i]   = expf(-m2) + noise[b * NN + i] * 1e-6f;
        rowmax[b * NN + i] = mx;
    }
}

__global__ __launch_bounds__(256) void k_distmax(
    const float* __restrict__ rowmax, float* __restrict__ dmax)
{
    int b = blockIdx.x, t = threadIdx.x;
    float m = 0.f;
    for (int i = t; i < NN; i += 256) m = fmaxf(m, rowmax[b * NN + i]);
    __shared__ float red[256];
    red[t] = m; __syncthreads();
    for (int o = 128; o > 0; o >>= 1) {
        if (t < o) red[t] = fmaxf(red[t], red[t + o]);
        __syncthreads();
    }
    if (t == 0) dmax[b] = red[0];
}

__global__ __launch_bounds__(256) void k_dmin(
    const float* __restrict__ x, const float* __restrict__ sq,
    const float* __restrict__ dens, const float* __restrict__ dmax,
    float* __restrict__ score)
{
    const int b  = blockIdx.y;
    const int i0 = blockIdx.x * 64;
    const float* xb  = x + (size_t)b * NN * CC;
    const float* sqb = sq + b * NN;
    const float* dnb = dens + b * NN;
    __shared__ float As[16][64];
    __shared__ float Bs[16][64];
    __shared__ float mrgmin[64][16];
    const int t  = threadIdx.x;
    const int tx = t & 15, ty = t >> 4;
    const int lr = t >> 2, lk4 = (t & 3) * 4;

    float sqi[4], di[4], mn[4];
    #pragma unroll
    for (int r = 0; r < 4; ++r) {
        sqi[r] = sqb[i0 + ty * 4 + r];
        di[r]  = dnb[i0 + ty * 4 + r];
        mn[r]  = 1e30f;
    }

    for (int j0 = 0; j0 < NN; j0 += 64) {
        float acc[4][4];
        #pragma unroll
        for (int r = 0; r < 4; ++r)
            #pragma unroll
            for (int s = 0; s < 4; ++s) acc[r][s] = 0.f;

        for (int k0 = 0; k0 < CC; k0 += 16) {
            float4 av = *(const float4*)(xb + (size_t)(i0 + lr) * CC + k0 + lk4);
            float4 bv = *(const float4*)(xb + (size_t)(j0 + lr) * CC + k0 + lk4);
            As[lk4 + 0][lr] = av.x; As[lk4 + 1][lr] = av.y;
            As[lk4 + 2][lr] = av.z; As[lk4 + 3][lr] = av.w;
            Bs[lk4 + 0][lr] = bv.x; Bs[lk4 + 1][lr] = bv.y;
            Bs[lk4 + 2][lr] = bv.z; Bs[lk4 + 3][lr] = bv.w;
            __syncthreads();
            #pragma unroll
            for (int kk = 0; kk < 16; ++kk) {
                float4 a4 = *(const float4*)&As[kk][ty * 4];
                float4 b4 = *(const float4*)&Bs[kk][tx * 4];
                float ar[4] = {a4.x, a4.y, a4.z, a4.w};
                float br[4] = {b4.x, b4.y, b4.z, b4.w};
                #pragma unroll
                for (int r = 0; r < 4; ++r)
                    #pragma unroll
                    for (int s = 0; s < 4; ++s)
                        acc[r][s] = fmaf(ar[r], br[s], acc[r][s]);
            }
            __syncthreads();
        }
        float dj[4];
        #pragma unroll
        for (int s = 0; s < 4; ++s) dj[s] = dnb[j0 + tx * 4 + s];
        float sqj[4];
        #pragma unroll
        for (int s = 0; s < 4; ++s) sqj[s] = sqb[j0 + tx * 4 + s];
        #pragma unroll
        for (int r = 0; r < 4; ++r) {
            #pragma unroll
            for (int s = 0; s < 4; ++s) {
                float d2 = sqi[r] + sqj[s] - 2.0f * acc[r][s];
                float d  = sqrtf(fmaxf(d2, 0.0f)) * RSQC;
                if (dj[s] > di[r]) mn[r] = fminf(mn[r], d);
            }
        }
    }
    #pragma unroll
    for (int r = 0; r < 4; ++r) mrgmin[ty * 4 + r][tx] = mn[r];
    __syncthreads();
    if (t < 64) {
        float m = 1e30f;
        for (int c = 0; c < 16; ++c) m = fminf(m, mrgmin[t][c]);
        float dm = fminf(dmax[b], m);
        score[b * NN + i0 + t] = dm * dnb[i0 + t];
    }
}

__global__ __launch_bounds__(256) void k_assign(
    const float* __restrict__ x, const float* __restrict__ sq,
    const int* __restrict__ idown, int* __restrict__ idxc)
{
    const int b  = blockIdx.y;
    const int n0 = blockIdx.x * 64;
    const float* xb  = x + (size_t)b * NN * CC;
    const float* sqb = sq + b * NN;
    const int* idb = idown + b * KCL;
    __shared__ float As[16][64];
    __shared__ float Bs[16][64];
    __shared__ float mv[64][16];
    __shared__ int   mk[64][16];
    const int t  = threadIdx.x;
    const int tx = t & 15, ty = t >> 4;
    const int lr = t >> 2, lk4 = (t & 3) * 4;

    float sqt[4];
    #pragma unroll
    for (int s = 0; s < 4; ++s) sqt[s] = sqb[n0 + tx * 4 + s];
    float bestv[4] = {1e30f, 1e30f, 1e30f, 1e30f};
    int   bestk[4] = {0, 0, 0, 0};

    for (int c0 = 0; c0 < KCL; c0 += 64) {
        int crow = idb[c0 + lr];
        float acc[4][4];
        #pragma unroll
        for (int r = 0; r < 4; ++r)
            #pragma unroll
            for (int s = 0; s < 4; ++s) acc[r][s] = 0.f;

        for (int k0 = 0; k0 < CC; k0 += 16) {
            float4 av = *(const float4*)(xb + (size_t)crow * CC + k0 + lk4);
            float4 bv = *(const float4*)(xb + (size_t)(n0 + lr) * CC + k0 + lk4);
            As[lk4 + 0][lr] = av.x; As[lk4 + 1][lr] = av.y;
            As[lk4 + 2][lr] = av.z; As[lk4 + 3][lr] = av.w;
            Bs[lk4 + 0][lr] = bv.x; Bs[lk4 + 1][lr] = bv.y;
            Bs[lk4 + 2][lr] = bv.z; Bs[lk4 + 3][lr] = bv.w;
            __syncthreads();
            #pragma unroll
            for (int kk = 0; kk < 16; ++kk) {
                float4 a4 = *(const float4*)&As[kk][ty * 4];
                float4 b4 = *(const float4*)&Bs[kk][tx * 4];
                float ar[4] = {a4.x, a4.y, a4.z, a4.w};
                float br[4] = {b4.x, b4.y, b4.z, b4.w};
                #pragma unroll
                for (int r = 0; r < 4; ++r)
                    #pragma unroll
                    for (int s = 0; s < 4; ++s)
                        acc[r][s] = fmaf(ar[r], br[s], acc[r][s]);
            }
            __syncthreads();
        }
        float sqc[4];
        #pragma unroll
        for (int r = 0; r < 4; ++r) sqc[r] = sqb[idb[c0 + ty * 4 + r]];
        #pragma unroll
        for (int r = 0; r < 4; ++r) {
            int kg = c0 + ty * 4 + r;
            #pragma unroll
            for (int s = 0; s < 4; ++s) {
                float e = fmaxf(sqc[r] + sqt[s] - 2.0f * acc[r][s], 0.0f);
                if (e < bestv[s]) { bestv[s] = e; bestk[s] = kg; }
            }
        }
    }
    #pragma unroll
    for (int s = 0; s < 4; ++s) {
        mv[tx * 4 + s][ty] = bestv[s];
        mk[tx * 4 + s][ty] = bestk[s];
    }
    __syncthreads();
    if (t < 64) {
        float bv = 1e30f; int bk = 1 << 30;
        for (int c = 0; c < 16; ++c) {
            float v = mv[t][c]; int k = mk[t][c];
            if (v < bv || (v == bv && k < bk)) { bv = v; bk = k; }
        }
        idxc[b * NN + n0 + t] = bk;
    }
}

__global__ __launch_bounds__(256) void k_override(
    const int* __restrict__ idown, int* __restrict__ idxc)
{
    int g = blockIdx.x * 256 + threadIdx.x;
    int b = g >> 9, k = g & 511;
    idxc[b * NN + idown[g]] = k;
}

// ======================= shared tail kernels =======================

__global__ __launch_bounds__(1024) void k_topk(
    const float* __restrict__ score, int* __restrict__ idown, int* __restrict__ invc)
{
    int b = blockIdx.x, t = threadIdx.x;
    __shared__ float s[NN];
    __shared__ int   si[NN];
    s[t]         = score[b * NN + t];        si[t]        = t;
    s[t + 1024]  = score[b * NN + t + 1024]; si[t + 1024] = t + 1024;
    __syncthreads();
    for (int k = 2; k <= NN; k <<= 1) {
        for (int j = k >> 1; j > 0; j >>= 1) {
            int i = (t & (j - 1)) | ((t & ~(j - 1)) << 1);
            int l = i | j;
            bool dir = ((i & k) == 0);
            float svi = s[i], svl = s[l];
            int   ii  = si[i], il = si[l];
            bool before_l_i = (svl > svi) || (svl == svi && il < ii);
            if (before_l_i == dir) {
                s[i] = svl; s[l] = svi;
                si[i] = il; si[l] = ii;
            }
            __syncthreads();
        }
    }
    if (t < KCL) idown[b * KCL + t] = si[t];
    invc[b * NN + t] = -1;
    invc[b * NN + t + 1024] = -1;
    __syncthreads();
    if (t < KCL) invc[b * NN + si[t]] = t;
}

__global__ __launch_bounds__(512) void k_merge(
    const float* __restrict__ x, const float* __restrict__ tw,
    const int* __restrict__ idxc, float* __restrict__ aw, float* __restrict__ xm)
{
    int b = blockIdx.y, k = blockIdx.x;
    __shared__ int members[NN];
    __shared__ int wc[8];
    __shared__ float red[512];
    int t = threadIdx.x, lane = t & 63, w = t >> 6;
    const int* ib = idxc + b * NN;
    int base = 0;
    for (int r0 = 0; r0 < NN; r0 += 512) {
        int n = r0 + t;
        bool m = (ib[n] == k);
        unsigned long long msk = __ballot(m);
        if (lane == 0) wc[w] = __popcll(msk);
        __syncthreads();
        int off = 0;
        for (int ww = 0; ww < w; ++ww) off += wc[ww];
        int tot = 0;
        #pragma unroll
        for (int ww = 0; ww < 8; ++ww) tot += wc[ww];
        if (m) members[base + off + __popcll(msk & ((1ull << lane) - 1ull))] = n;
        base += tot;
        __syncthreads();
    }
    int cnt = base;
    const float* twb = tw + b * NN;
    float ps = 0.f;
    for (int p = t; p < cnt; p += 512) ps += twb[members[p]];
    red[t] = ps; __syncthreads();
    for (int o = 256; o > 0; o >>= 1) {
        if (t < o) red[t] += red[t + o];
        __syncthreads();
    }
    float awf = red[0] + 1e-6f;
    if (t == 0) aw[b * KCL + k] = awf;
    if (t < CC) {
        const float* xb = x + (size_t)b * NN * CC;
        float s = 0.f;
        for (int p = 0; p < cnt; ++p) {
            int n = members[p];
            s += xb[(size_t)n * CC + t] * twb[n];
        }
        xm[((size_t)b * KCL + k) * CC + t] = s / awf;
    }
}

__global__ __launch_bounds__(256) void k_out(
    const int* __restrict__ idx_token, const float* __restrict__ aggw,
    const float* __restrict__ tw, const float* __restrict__ aw,
    const int* __restrict__ idxc, float* __restrict__ out_idx,
    float* __restrict__ out_agg)
{
    int g = blockIdx.x * 256 + threadIdx.x;
    int b = g >> 11;
    int it = idx_token[g];
    int kclu = idxc[b * NN + it];
    out_idx[g] = (float)kclu;
    float nw = tw[b * NN + it] / aw[b * KCL + kclu];
    out_agg[g] = aggw[g] * nw;
}

extern "C" void kernel_launch(void* const* d_in, const int* in_sizes, int n_in,
                              void* d_out, int out_size, void* d_ws, size_t ws_size,
                              hipStream_t stream) {
    const float* x         = (const float*)d_in[0];
    const int*   idx_token = (const int*)  d_in[1];
    const float* aggw      = (const float*)d_in[2];
    const float* noise     = (const float*)d_in[3];
    const float* sw        = (const float*)d_in[4];
    const float* sb        = (const float*)d_in[5];

    float* ws      = (float*)d_ws;
    float* sq      = ws;                 // B*N
    float* tw      = ws + 32768;         // B*N
    float* dens    = ws + 65536;         // B*N
    float* rowmax  = ws + 98304;         // B*N (PATH B)
    float* score   = ws + 131072;        // B*N
    unsigned* dmaxraw = (unsigned*)(ws + 163840); // 64 slots (PATH A); PATH B float dmax
    float* aw      = ws + 163904;        // B*512
    int*   idown   = (int*)(ws + 172096);// B*512
    int*   idxc    = (int*)(ws + 180288);// B*N
    int*   invc    = (int*)(ws + 213056);// B*N -> ends 245824

    unsigned short* Xh = (unsigned short*)(ws + 245824);
    unsigned short* Xl = (unsigned short*)(ws + 245824 + 6291456);
    float* Dbuf        = ws + 245824 + 2 * 6291456;

    const size_t head_bytes = (size_t)(245824 + 2 * 6291456) * 4;
    size_t avail = (ws_size > head_bytes) ? (ws_size - head_bytes) : 0;
    int nbg = 0;
    for (int g = 16; g >= 1; g >>= 1) {
        if ((size_t)g * NN * NN * 4 <= avail) { nbg = g; break; }
    }

    float* xm      = (float*)d_out;                      // B*512*C
    float* out_idx = xm + (size_t)BB * KCL * CC;         // B*N
    float* out_agg = out_idx + (size_t)BB * NN;          // B*N

    if (nbg >= 16) {
        k_prep    <<<dim3(BB * NN / 4), 256, 0, stream>>>(x, sw, sb, sq, tw, Xh, Xl, dmaxraw);
        k_gemm_sym<<<dim3(136, 1, BB), 256, 0, stream>>>(Xh, Xl, sq, Dbuf, 0);
        k_density2<<<dim3(BB * NN / 4), 256, 0, stream>>>(Dbuf, noise, dens, dmaxraw);
        k_dmin2   <<<dim3(BB * NN / 4), 256, 0, stream>>>(Dbuf, dens, dmaxraw, score);
        k_topk    <<<dim3(BB), 1024, 0, stream>>>(score, idown, invc);
        k_assign2 <<<dim3(NN / 64, BB), 256, 0, stream>>>(Dbuf, idown, invc, idxc);
    } else if (nbg >= 1) {
        k_prep<<<dim3(BB * NN / 4), 256, 0, stream>>>(x, sw, sb, sq, tw, Xh, Xl, dmaxraw);
        int G = (nbg >= 8) ? 8 : nbg;
        for (int b0 = 0; b0 < BB; b0 += G) {
            int g = (b0 + G <= BB) ? G : (BB - b0);
            k_gemm_sym<<<dim3(136, 1, g), 256, 0, stream>>>(Xh, Xl, sq, Dbuf, b0);
            k_density2<<<dim3(g * NN / 4), 256, 0, stream>>>(Dbuf, noise + b0 * NN,
                                                             dens + b0 * NN, dmaxraw + b0);
            k_dmin2   <<<dim3(g * NN / 4), 256, 0, stream>>>(Dbuf, dens + b0 * NN,
                                                             dmaxraw + b0, score + b0 * NN);
            k_topk    <<<dim3(g), 1024, 0, stream>>>(score + b0 * NN, idown + b0 * KCL,
                                                     invc + b0 * NN);
            k_assign2 <<<dim3(NN / 64, g), 256, 0, stream>>>(Dbuf, idown + b0 * KCL,
                                                             invc + b0 * NN, idxc + b0 * NN);
        }
    } else {
        float* dmaxf = (float*)dmaxraw;
        k_rowstats<<<dim3(BB * NN / 4), 256, 0, stream>>>(x, sw, sb, sq, tw);
        k_density <<<dim3(NN / 64, BB), 256, 0, stream>>>(x, sq, noise, dens, rowmax);
        k_distmax <<<dim3(BB), 256, 0, stream>>>(rowmax, dmaxf);
        k_dmin    <<<dim3(NN / 64, BB), 256, 0, stream>>>(x, sq, dens, dmaxf, score);
        k_topk    <<<dim3(BB), 1024, 0, stream>>>(score, idown, invc);
        k_assign  <<<dim3(NN / 64, BB), 256, 0, stream>>>(x, sq, idown, idxc);
        k_override<<<dim3(BB * KCL / 256), 256, 0, stream>>>(idown, idxc);
    }

    k_merge<<<dim3(KCL, BB), 512, 0, stream>>>(x, tw, idxc, aw, xm);
    k_out  <<<dim3(BB * NN / 256), 256, 0, stream>>>(idx_token, aggw, tw, aw, idxc,
                                                     out_idx, out_agg);
}

// Round 14
// 444.082 us; speedup vs baseline: 1.1167x; 1.1167x over previous
//
#include <hip/hip_runtime.h>
#include <math.h>

static constexpr int BB  = 16;
static constexpr int NN  = 2048;
static constexpr int CC  = 384;
static constexpr int KCL = 512;
static constexpr float RSQC = 0.051031036307982884f; // 1/sqrt(384)

typedef short  bf16x8 __attribute__((ext_vector_type(8)));
typedef float  f32x4  __attribute__((ext_vector_type(4)));

__device__ __forceinline__ unsigned short f2b(float v) {
    unsigned u = __float_as_uint(v);
    unsigned r = (u + 0x7FFFu + ((u >> 16) & 1u)) >> 16; // RNE
    return (unsigned short)r;
}
__device__ __forceinline__ float b2f(unsigned short b) {
    return __uint_as_float(((unsigned)b) << 16);
}
__device__ __forceinline__ void gload16(const void* g, void* l) {
    __builtin_amdgcn_global_load_lds(
        (const __attribute__((address_space(1))) void*)g,
        (__attribute__((address_space(3))) void*)l, 16, 0, 0);
}
__device__ __forceinline__ void ins5(float* t5, float v) {
    if (v < t5[4]) {
        t5[4] = v;
        #pragma unroll
        for (int q = 4; q > 0; --q) {
            if (t5[q] < t5[q - 1]) { float tmp = t5[q - 1]; t5[q - 1] = t5[q]; t5[q] = tmp; }
        }
    }
}

// ---------------- kernel 0 (fused): |x|^2, token weight, hi/lo bf16 split ----------------
__global__ __launch_bounds__(256) void k_prep(
    const float* __restrict__ x, const float* __restrict__ sw,
    const float* __restrict__ sb, float* __restrict__ sq, float* __restrict__ tw,
    unsigned short* __restrict__ Xh, unsigned short* __restrict__ Xl)
{
    int row  = blockIdx.x * 4 + (threadIdx.x >> 6);
    int lane = threadIdx.x & 63;
    const float* xr = x + (size_t)row * CC;
    unsigned short* xh = Xh + (size_t)row * CC;
    unsigned short* xl = Xl + (size_t)row * CC;
    float s2 = 0.f, sd = 0.f;
    for (int c = lane; c < CC; c += 64) {
        float v = xr[c];
        s2 += v * v;
        sd += v * sw[c];
        unsigned short h = f2b(v);
        xh[c] = h;
        xl[c] = f2b(v - b2f(h));
    }
    #pragma unroll
    for (int o = 32; o > 0; o >>= 1) {
        s2 += __shfl_down(s2, o);
        sd += __shfl_down(sd, o);
    }
    if (lane == 0) {
        sq[row] = s2;
        tw[row] = expf(sd + sb[0]);
    }
}

// ---------------- fallback: per-row |x|^2 and token weight ----------------
__global__ __launch_bounds__(256) void k_rowstats(
    const float* __restrict__ x, const float* __restrict__ sw,
    const float* __restrict__ sb, float* __restrict__ sq, float* __restrict__ tw)
{
    int row  = blockIdx.x * 4 + (threadIdx.x >> 6);
    int lane = threadIdx.x & 63;
    const float* xr = x + (size_t)row * CC;
    float s2 = 0.f, sd = 0.f;
    for (int c = lane; c < CC; c += 64) {
        float v = xr[c];
        s2 += v * v;
        sd += v * sw[c];
    }
    #pragma unroll
    for (int o = 32; o > 0; o >>= 1) {
        s2 += __shfl_down(s2, o);
        sd += __shfl_down(sd, o);
    }
    if (lane == 0) {
        sq[row] = s2;
        tw[row] = expf(sd + sb[0]);
    }
}

// ======================= PATH A: stored-D pipeline =======================

// Symmetric split-bf16 MFMA GEMM over upper-triangle 128x128 tiles.
// Single-buffered global_load_lds staging (33KB LDS -> 4 blocks/CU). R7-verified.
__global__ __launch_bounds__(256) void k_gemm_sym(
    const unsigned short* __restrict__ Xh, const unsigned short* __restrict__ Xl,
    const float* __restrict__ sq, float* __restrict__ D, int b0)
{
    const int b = b0 + blockIdx.z;
    int q = blockIdx.x;
    int ti = 0;
    while (q >= (16 - ti)) { q -= (16 - ti); ++ti; }
    const int tj = ti + q;
    const int i0 = ti * 128, j0 = tj * 128;

    const unsigned short* Xhb = Xh + (size_t)b * NN * CC;
    const unsigned short* Xlb = Xl + (size_t)b * NN * CC;
    const float* sqb = sq + b * NN;
    float* Db = D + (size_t)blockIdx.z * NN * NN;

    __shared__ union {
        unsigned short u16[4][128][32]; // [plane][row][k-slot*8]
        float tr[64][129];              // transpose buffer (epilogue only)
    } sm;

    const int t  = threadIdx.x;
    const int w  = t >> 6;
    const int l  = t & 63;
    const int wr = w >> 1, wc = w & 1;
    const int lt = l & 15, sl = l >> 4;

    f32x4 acc[4][4];
    #pragma unroll
    for (int fr = 0; fr < 4; ++fr)
        #pragma unroll
        for (int fc = 0; fc < 4; ++fc) acc[fr][fc] = (f32x4)0.0f;

    for (int kc = 0; kc < CC; kc += 32) {
        #pragma unroll
        for (int p = 0; p < 4; ++p) {
            const unsigned short* src = (p == 0) ? Xhb : (p == 1) ? Xlb
                                      : (p == 2) ? Xhb : Xlb;
            const int base0 = (p < 2) ? i0 : j0;
            #pragma unroll
            for (int u = 0; u < 2; ++u) {
                int seg = w * 2 + u;
                int r   = seg * 16 + (l >> 2);
                int s   = (l & 3) ^ ((r >> 1) & 3);
                gload16(src + (size_t)(base0 + r) * CC + kc + s * 8,
                        &sm.u16[p][seg * 16][0]);
            }
        }
        __syncthreads();

        bf16x8 fah[4], fal[4], fbh[4], fbl[4];
        #pragma unroll
        for (int fr = 0; fr < 4; ++fr) {
            int ra = wr * 64 + fr * 16 + lt;
            int sa = (sl ^ ((ra >> 1) & 3)) * 8;
            fah[fr] = *(const bf16x8*)&sm.u16[0][ra][sa];
            fal[fr] = *(const bf16x8*)&sm.u16[1][ra][sa];
        }
        #pragma unroll
        for (int fc = 0; fc < 4; ++fc) {
            int rb = wc * 64 + fc * 16 + lt;
            int sb_ = (sl ^ ((rb >> 1) & 3)) * 8;
            fbh[fc] = *(const bf16x8*)&sm.u16[2][rb][sb_];
            fbl[fc] = *(const bf16x8*)&sm.u16[3][rb][sb_];
        }
        #pragma unroll
        for (int fr = 0; fr < 4; ++fr)
            #pragma unroll
            for (int fc = 0; fc < 4; ++fc) {
                acc[fr][fc] = __builtin_amdgcn_mfma_f32_16x16x32_bf16(
                    fah[fr], fbh[fc], acc[fr][fc], 0, 0, 0);
                acc[fr][fc] = __builtin_amdgcn_mfma_f32_16x16x32_bf16(
                    fah[fr], fbl[fc], acc[fr][fc], 0, 0, 0);
                acc[fr][fc] = __builtin_amdgcn_mfma_f32_16x16x32_bf16(
                    fal[fr], fbh[fc], acc[fr][fc], 0, 0, 0);
            }
        __syncthreads();
    }

    float sqr[4][4], sqc[4];
    #pragma unroll
    for (int fr = 0; fr < 4; ++fr)
        #pragma unroll
        for (int reg = 0; reg < 4; ++reg)
            sqr[fr][reg] = sqb[i0 + wr * 64 + fr * 16 + sl * 4 + reg];
    #pragma unroll
    for (int fc = 0; fc < 4; ++fc)
        sqc[fc] = sqb[j0 + wc * 64 + fc * 16 + lt];

    #pragma unroll
    for (int fr = 0; fr < 4; ++fr)
        #pragma unroll
        for (int fc = 0; fc < 4; ++fc)
            #pragma unroll
            for (int reg = 0; reg < 4; ++reg) {
                int row = i0 + wr * 64 + fr * 16 + sl * 4 + reg;
                int col = j0 + wc * 64 + fc * 16 + lt;
                float d2 = fmaxf(sqr[fr][reg] + sqc[fc] - 2.0f * acc[fr][fc][reg], 0.0f);
                Db[(size_t)row * NN + col] = d2;
            }

    if (ti != tj) {
        #pragma unroll
        for (int h = 0; h < 2; ++h) {
            __syncthreads();
            if (wr == h) {
                #pragma unroll
                for (int fr = 0; fr < 4; ++fr)
                    #pragma unroll
                    for (int fc = 0; fc < 4; ++fc)
                        #pragma unroll
                        for (int reg = 0; reg < 4; ++reg) {
                            int rl = fr * 16 + sl * 4 + reg;
                            int cl = wc * 64 + fc * 16 + lt;
                            float d2 = fmaxf(sqr[fr][reg] + sqc[fc]
                                             - 2.0f * acc[fr][fc][reg], 0.0f);
                            sm.tr[rl][cl] = d2;
                        }
            }
            __syncthreads();
            for (int idx = t; idx < 128 * 64; idx += 256) {
                int c  = idx >> 6;
                int rl = idx & 63;
                Db[(size_t)(j0 + c) * NN + i0 + h * 64 + rl] = sm.tr[rl][c];
            }
        }
    }
}

// density from stored D: one wave per row (top5 d2 + max d2)
__global__ __launch_bounds__(256) void k_density2(
    const float* __restrict__ D, const float* __restrict__ noise,
    float* __restrict__ dens, float* __restrict__ rowmax)
{
    int gid  = blockIdx.x * 4 + (threadIdx.x >> 6);
    int lane = threadIdx.x & 63;
    const float* row = D + (size_t)gid * NN;
    float t5[5] = {1e30f, 1e30f, 1e30f, 1e30f, 1e30f};
    float mx = 0.f;
    #pragma unroll
    for (int it = 0; it < 8; ++it) {
        float4 v = ((const float4*)row)[it * 64 + lane];
        mx = fmaxf(mx, fmaxf(fmaxf(v.x, v.y), fmaxf(v.z, v.w)));
        ins5(t5, v.x); ins5(t5, v.y); ins5(t5, v.z); ins5(t5, v.w);
    }
    #pragma unroll
    for (int o = 1; o < 64; o <<= 1) {
        float b0 = __shfl_xor(t5[0], o), b1 = __shfl_xor(t5[1], o);
        float b2 = __shfl_xor(t5[2], o), b3 = __shfl_xor(t5[3], o);
        float b4 = __shfl_xor(t5[4], o);
        mx = fmaxf(mx, __shfl_xor(mx, o));
        ins5(t5, b0); ins5(t5, b1); ins5(t5, b2); ins5(t5, b3); ins5(t5, b4);
    }
    if (lane == 0) {
        float m2 = (t5[0] + t5[1] + t5[2] + t5[3] + t5[4]) * (1.0f / (5.0f * CC));
        dens[gid]   = expf(-m2) + noise[gid] * 1e-6f;
        rowmax[gid] = mx; // max d2
    }
}

// per-batch dist max (input is d2, output is d)
__global__ __launch_bounds__(256) void k_distmax2(
    const float* __restrict__ rowmax, float* __restrict__ dmax)
{
    int b = blockIdx.x, t = threadIdx.x;
    float m = 0.f;
    for (int i = t; i < NN; i += 256) m = fmaxf(m, rowmax[b * NN + i]);
    __shared__ float red[256];
    red[t] = m; __syncthreads();
    for (int o = 128; o > 0; o >>= 1) {
        if (t < o) red[t] = fmaxf(red[t], red[t + o]);
        __syncthreads();
    }
    if (t == 0) dmax[b] = sqrtf(red[0]) * RSQC;
}

// dmin from stored D
__global__ __launch_bounds__(256) void k_dmin2(
    const float* __restrict__ D, const float* __restrict__ dens,
    const float* __restrict__ dmax, float* __restrict__ score)
{
    int gid  = blockIdx.x * 4 + (threadIdx.x >> 6);
    int lane = threadIdx.x & 63;
    int bl   = gid >> 11;
    const float* row = D + (size_t)gid * NN;
    const float* dn  = dens + (size_t)bl * NN;
    float di = dens[gid];
    float m = 1e30f;
    #pragma unroll
    for (int it = 0; it < 8; ++it) {
        float4 v  = ((const float4*)row)[it * 64 + lane];
        float4 dj = ((const float4*)dn)[it * 64 + lane];
        if (dj.x > di) m = fminf(m, v.x);
        if (dj.y > di) m = fminf(m, v.y);
        if (dj.z > di) m = fminf(m, v.z);
        if (dj.w > di) m = fminf(m, v.w);
    }
    #pragma unroll
    for (int o = 32; o > 0; o >>= 1) m = fminf(m, __shfl_down(m, o));
    if (lane == 0) {
        float dm = fminf(sqrtf(m) * RSQC, dmax[bl]);
        score[gid] = dm * di;
    }
}

// token -> nearest center from stored D, 4-way split-K; invc folds the override
__global__ __launch_bounds__(256) void k_assign2(
    const float* __restrict__ D, const int* __restrict__ idown,
    const int* __restrict__ invc, int* __restrict__ idxc)
{
    int bl = blockIdx.y;
    int tl = threadIdx.x & 63;
    int g  = threadIdx.x >> 6;
    int n  = blockIdx.x * 64 + tl;
    const float* Db = D + (size_t)bl * NN * NN;
    const int* idb  = idown + bl * KCL;
    float best = 1e30f; int bk = 0;
    for (int k = g * 128; k < (g + 1) * 128; ++k) {
        float v = Db[(size_t)idb[k] * NN + n];
        if (v < best) { best = v; bk = k; }
    }
    __shared__ float bvs[4][64];
    __shared__ int   bks[4][64];
    bvs[g][tl] = best; bks[g][tl] = bk;
    __syncthreads();
    if (threadIdx.x < 64) {
        float bv = bvs[0][threadIdx.x]; int bkk = bks[0][threadIdx.x];
        #pragma unroll
        for (int gg = 1; gg < 4; ++gg) {
            if (bvs[gg][threadIdx.x] < bv) { bv = bvs[gg][threadIdx.x]; bkk = bks[gg][threadIdx.x]; }
        }
        int nn = blockIdx.x * 64 + threadIdx.x;
        int iv = invc[bl * NN + nn];
        idxc[bl * NN + nn] = (iv >= 0) ? iv : bkk;
    }
}

// ======================= PATH B: recompute pipeline (fallback) =======================

__global__ __launch_bounds__(256) void k_density(
    const float* __restrict__ x, const float* __restrict__ sq,
    const float* __restrict__ noise, float* __restrict__ dens,
    float* __restrict__ rowmax)
{
    const int b  = blockIdx.y;
    const int i0 = blockIdx.x * 64;
    const float* xb  = x + (size_t)b * NN * CC;
    const float* sqb = sq + b * NN;
    __shared__ float As[16][64];
    __shared__ float Bs[16][64];
    __shared__ float mrg[64][16][5];
    __shared__ float mrgmax[64][16];
    const int t  = threadIdx.x;
    const int tx = t & 15, ty = t >> 4;
    const int lr = t >> 2, lk4 = (t & 3) * 4;

    float top[4][5];
    float rmax[4];
    float sqi[4];
    #pragma unroll
    for (int r = 0; r < 4; ++r) {
        sqi[r]  = sqb[i0 + ty * 4 + r];
        rmax[r] = 0.f;
        #pragma unroll
        for (int q = 0; q < 5; ++q) top[r][q] = 1e30f;
    }

    for (int j0 = 0; j0 < NN; j0 += 64) {
        float acc[4][4];
        #pragma unroll
        for (int r = 0; r < 4; ++r)
            #pragma unroll
            for (int s = 0; s < 4; ++s) acc[r][s] = 0.f;

        for (int k0 = 0; k0 < CC; k0 += 16) {
            float4 av = *(const float4*)(xb + (size_t)(i0 + lr) * CC + k0 + lk4);
            float4 bv = *(const float4*)(xb + (size_t)(j0 + lr) * CC + k0 + lk4);
            As[lk4 + 0][lr] = av.x; As[lk4 + 1][lr] = av.y;
            As[lk4 + 2][lr] = av.z; As[lk4 + 3][lr] = av.w;
            Bs[lk4 + 0][lr] = bv.x; Bs[lk4 + 1][lr] = bv.y;
            Bs[lk4 + 2][lr] = bv.z; Bs[lk4 + 3][lr] = bv.w;
            __syncthreads();
            #pragma unroll
            for (int kk = 0; kk < 16; ++kk) {
                float4 a4 = *(const float4*)&As[kk][ty * 4];
                float4 b4 = *(const float4*)&Bs[kk][tx * 4];
                float ar[4] = {a4.x, a4.y, a4.z, a4.w};
                float br[4] = {b4.x, b4.y, b4.z, b4.w};
                #pragma unroll
                for (int r = 0; r < 4; ++r)
                    #pragma unroll
                    for (int s = 0; s < 4; ++s)
                        acc[r][s] = fmaf(ar[r], br[s], acc[r][s]);
            }
            __syncthreads();
        }
        float sqj[4];
        #pragma unroll
        for (int s = 0; s < 4; ++s) sqj[s] = sqb[j0 + tx * 4 + s];
        #pragma unroll
        for (int r = 0; r < 4; ++r) {
            #pragma unroll
            for (int s = 0; s < 4; ++s) {
                float d2 = sqi[r] + sqj[s] - 2.0f * acc[r][s];
                float d  = sqrtf(fmaxf(d2, 0.0f)) * RSQC;
                rmax[r] = fmaxf(rmax[r], d);
                if (d < top[r][4]) {
                    top[r][4] = d;
                    #pragma unroll
                    for (int q = 4; q > 0; --q) {
                        if (top[r][q] < top[r][q - 1]) {
                            float tmp = top[r][q - 1];
                            top[r][q - 1] = top[r][q];
                            top[r][q] = tmp;
                        }
                    }
                }
            }
        }
    }
    #pragma unroll
    for (int r = 0; r < 4; ++r) {
        #pragma unroll
        for (int q = 0; q < 5; ++q) mrg[ty * 4 + r][tx][q] = top[r][q];
        mrgmax[ty * 4 + r][tx] = rmax[r];
    }
    __syncthreads();
    if (t < 64) {
        float t5[5] = {1e30f, 1e30f, 1e30f, 1e30f, 1e30f};
        float mx = 0.f;
        for (int c = 0; c < 16; ++c) {
            mx = fmaxf(mx, mrgmax[t][c]);
            #pragma unroll
            for (int q = 0; q < 5; ++q) ins5(t5, mrg[t][c][q]);
        }
        float m2 = (t5[0]*t5[0] + t5[1]*t5[1] + t5[2]*t5[2] +
                    t5[3]*t5[3] + t5[4]*t5[4]) / 5.0f;
        int i = i0 + t;
        dens[b * NN + i]   = expf(-m2) + noise[b * NN + i] * 1e-6f;
        rowmax[b * NN + i] = mx;
    }
}

__global__ __launch_bounds__(256) void k_distmax(
    const float* __restrict__ rowmax, float* __restrict__ dmax)
{
    int b = blockIdx.x, t = threadIdx.x;
    float m = 0.f;
    for (int i = t; i < NN; i += 256) m = fmaxf(m, rowmax[b * NN + i]);
    __shared__ float red[256];
    red[t] = m; __syncthreads();
    for (int o = 128; o > 0; o >>= 1) {
        if (t < o) red[t] = fmaxf(red[t], red[t + o]);
        __syncthreads();
    }
    if (t == 0) dmax[b] = red[0];
}

__global__ __launch_bounds__(256) void k_dmin(
    const float* __restrict__ x, const float* __restrict__ sq,
    const float* __restrict__ dens, const float* __restrict__ dmax,
    float* __restrict__ score)
{
    const int b  = blockIdx.y;
    const int i0 = blockIdx.x * 64;
    const float* xb  = x + (size_t)b * NN * CC;
    const float* sqb = sq + b * NN;
    const float* dnb = dens + b * NN;
    __shared__ float As[16][64];
    __shared__ float Bs[16][64];
    __shared__ float mrgmin[64][16];
    const int t  = threadIdx.x;
    const int tx = t & 15, ty = t >> 4;
    const int lr = t >> 2, lk4 = (t & 3) * 4;

    float sqi[4], di[4], mn[4];
    #pragma unroll
    for (int r = 0; r < 4; ++r) {
        sqi[r] = sqb[i0 + ty * 4 + r];
        di[r]  = dnb[i0 + ty * 4 + r];
        mn[r]  = 1e30f;
    }

    for (int j0 = 0; j0 < NN; j0 += 64) {
        float acc[4][4];
        #pragma unroll
        for (int r = 0; r < 4; ++r)
            #pragma unroll
            for (int s = 0; s < 4; ++s) acc[r][s] = 0.f;

        for (int k0 = 0; k0 < CC; k0 += 16) {
            float4 av = *(const float4*)(xb + (size_t)(i0 + lr) * CC + k0 + lk4);
            float4 bv = *(const float4*)(xb + (size_t)(j0 + lr) * CC + k0 + lk4);
            As[lk4 + 0][lr] = av.x; As[lk4 + 1][lr] = av.y;
            As[lk4 + 2][lr] = av.z; As[lk4 + 3][lr] = av.w;
            Bs[lk4 + 0][lr] = bv.x; Bs[lk4 + 1][lr] = bv.y;
            Bs[lk4 + 2][lr] = bv.z; Bs[lk4 + 3][lr] = bv.w;
            __syncthreads();
            #pragma unroll
            for (int kk = 0; kk < 16; ++kk) {
                float4 a4 = *(const float4*)&As[kk][ty * 4];
                float4 b4 = *(const float4*)&Bs[kk][tx * 4];
                float ar[4] = {a4.x, a4.y, a4.z, a4.w};
                float br[4] = {b4.x, b4.y, b4.z, b4.w};
                #pragma unroll
                for (int r = 0; r < 4; ++r)
                    #pragma unroll
                    for (int s = 0; s < 4; ++s)
                        acc[r][s] = fmaf(ar[r], br[s], acc[r][s]);
            }
            __syncthreads();
        }
        float dj[4];
        #pragma unroll
        for (int s = 0; s < 4; ++s) dj[s] = dnb[j0 + tx * 4 + s];
        float sqj[4];
        #pragma unroll
        for (int s = 0; s < 4; ++s) sqj[s] = sqb[j0 + tx * 4 + s];
        #pragma unroll
        for (int r = 0; r < 4; ++r) {
            #pragma unroll
            for (int s = 0; s < 4; ++s) {
                float d2 = sqi[r] + sqj[s] - 2.0f * acc[r][s];
                float d  = sqrtf(fmaxf(d2, 0.0f)) * RSQC;
                if (dj[s] > di[r]) mn[r] = fminf(mn[r], d);
            }
        }
    }
    #pragma unroll
    for (int r = 0; r < 4; ++r) mrgmin[ty * 4 + r][tx] = mn[r];
    __syncthreads();
    if (t < 64) {
        float m = 1e30f;
        for (int c = 0; c < 16; ++c) m = fminf(m, mrgmin[t][c]);
        float dm = fminf(dmax[b], m);
        score[b * NN + i0 + t] = dm * dnb[i0 + t];
    }
}

__global__ __launch_bounds__(256) void k_assign(
    const float* __restrict__ x, const float* __restrict__ sq,
    const int* __restrict__ idown, int* __restrict__ idxc)
{
    const int b  = blockIdx.y;
    const int n0 = blockIdx.x * 64;
    const float* xb  = x + (size_t)b * NN * CC;
    const float* sqb = sq + b * NN;
    const int* idb = idown + b * KCL;
    __shared__ float As[16][64];
    __shared__ float Bs[16][64];
    __shared__ float mv[64][16];
    __shared__ int   mk[64][16];
    const int t  = threadIdx.x;
    const int tx = t & 15, ty = t >> 4;
    const int lr = t >> 2, lk4 = (t & 3) * 4;

    float sqt[4];
    #pragma unroll
    for (int s = 0; s < 4; ++s) sqt[s] = sqb[n0 + tx * 4 + s];
    float bestv[4] = {1e30f, 1e30f, 1e30f, 1e30f};
    int   bestk[4] = {0, 0, 0, 0};

    for (int c0 = 0; c0 < KCL; c0 += 64) {
        int crow = idb[c0 + lr];
        float acc[4][4];
        #pragma unroll
        for (int r = 0; r < 4; ++r)
            #pragma unroll
            for (int s = 0; s < 4; ++s) acc[r][s] = 0.f;

        for (int k0 = 0; k0 < CC; k0 += 16) {
            float4 av = *(const float4*)(xb + (size_t)crow * CC + k0 + lk4);
            float4 bv = *(const float4*)(xb + (size_t)(n0 + lr) * CC + k0 + lk4);
            As[lk4 + 0][lr] = av.x; As[lk4 + 1][lr] = av.y;
            As[lk4 + 2][lr] = av.z; As[lk4 + 3][lr] = av.w;
            Bs[lk4 + 0][lr] = bv.x; Bs[lk4 + 1][lr] = bv.y;
            Bs[lk4 + 2][lr] = bv.z; Bs[lk4 + 3][lr] = bv.w;
            __syncthreads();
            #pragma unroll
            for (int kk = 0; kk < 16; ++kk) {
                float4 a4 = *(const float4*)&As[kk][ty * 4];
                float4 b4 = *(const float4*)&Bs[kk][tx * 4];
                float ar[4] = {a4.x, a4.y, a4.z, a4.w};
                float br[4] = {b4.x, b4.y, b4.z, b4.w};
                #pragma unroll
                for (int r = 0; r < 4; ++r)
                    #pragma unroll
                    for (int s = 0; s < 4; ++s)
                        acc[r][s] = fmaf(ar[r], br[s], acc[r][s]);
            }
            __syncthreads();
        }
        float sqc[4];
        #pragma unroll
        for (int r = 0; r < 4; ++r) sqc[r] = sqb[idb[c0 + ty * 4 + r]];
        #pragma unroll
        for (int r = 0; r < 4; ++r) {
            int kg = c0 + ty * 4 + r;
            #pragma unroll
            for (int s = 0; s < 4; ++s) {
                float e = fmaxf(sqc[r] + sqt[s] - 2.0f * acc[r][s], 0.0f);
                if (e < bestv[s]) { bestv[s] = e; bestk[s] = kg; }
            }
        }
    }
    #pragma unroll
    for (int s = 0; s < 4; ++s) {
        mv[tx * 4 + s][ty] = bestv[s];
        mk[tx * 4 + s][ty] = bestk[s];
    }
    __syncthreads();
    if (t < 64) {
        float bv = 1e30f; int bk = 1 << 30;
        for (int c = 0; c < 16; ++c) {
            float v = mv[t][c]; int k = mk[t][c];
            if (v < bv || (v == bv && k < bk)) { bv = v; bk = k; }
        }
        idxc[b * NN + n0 + t] = bk;
    }
}

__global__ __launch_bounds__(256) void k_override(
    const int* __restrict__ idown, int* __restrict__ idxc)
{
    int g = blockIdx.x * 256 + threadIdx.x;
    int b = g >> 9, k = g & 511;
    idxc[b * NN + idown[g]] = k;
}

// ======================= shared tail kernels =======================

__global__ __launch_bounds__(1024) void k_topk(
    const float* __restrict__ score, int* __restrict__ idown, int* __restrict__ invc)
{
    int b = blockIdx.x, t = threadIdx.x;
    __shared__ float s[NN];
    __shared__ int   si[NN];
    s[t]         = score[b * NN + t];        si[t]        = t;
    s[t + 1024]  = score[b * NN + t + 1024]; si[t + 1024] = t + 1024;
    __syncthreads();
    for (int k = 2; k <= NN; k <<= 1) {
        for (int j = k >> 1; j > 0; j >>= 1) {
            int i = (t & (j - 1)) | ((t & ~(j - 1)) << 1);
            int l = i | j;
            bool dir = ((i & k) == 0);
            float svi = s[i], svl = s[l];
            int   ii  = si[i], il = si[l];
            bool before_l_i = (svl > svi) || (svl == svi && il < ii);
            if (before_l_i == dir) {
                s[i] = svl; s[l] = svi;
                si[i] = il; si[l] = ii;
            }
            __syncthreads();
        }
    }
    if (t < KCL) idown[b * KCL + t] = si[t];
    invc[b * NN + t] = -1;
    invc[b * NN + t + 1024] = -1;
    __syncthreads();
    if (t < KCL) invc[b * NN + si[t]] = t;
}

__global__ __launch_bounds__(512) void k_merge(
    const float* __restrict__ x, const float* __restrict__ tw,
    const int* __restrict__ idxc, float* __restrict__ aw, float* __restrict__ xm)
{
    int b = blockIdx.y, k = blockIdx.x;
    __shared__ int members[NN];
    __shared__ int wc[8];
    __shared__ float red[512];
    int t = threadIdx.x, lane = t & 63, w = t >> 6;
    const int* ib = idxc + b * NN;
    int base = 0;
    for (int r0 = 0; r0 < NN; r0 += 512) {
        int n = r0 + t;
        bool m = (ib[n] == k);
        unsigned long long msk = __ballot(m);
        if (lane == 0) wc[w] = __popcll(msk);
        __syncthreads();
        int off = 0;
        for (int ww = 0; ww < w; ++ww) off += wc[ww];
        int tot = 0;
        #pragma unroll
        for (int ww = 0; ww < 8; ++ww) tot += wc[ww];
        if (m) members[base + off + __popcll(msk & ((1ull << lane) - 1ull))] = n;
        base += tot;
        __syncthreads();
    }
    int cnt = base;
    const float* twb = tw + b * NN;
    float ps = 0.f;
    for (int p = t; p < cnt; p += 512) ps += twb[members[p]];
    red[t] = ps; __syncthreads();
    for (int o = 256; o > 0; o >>= 1) {
        if (t < o) red[t] += red[t + o];
        __syncthreads();
    }
    float awf = red[0] + 1e-6f;
    if (t == 0) aw[b * KCL + k] = awf;
    if (t < CC) {
        const float* xb = x + (size_t)b * NN * CC;
        float s = 0.f;
        for (int p = 0; p < cnt; ++p) {
            int n = members[p];
            s += xb[(size_t)n * CC + t] * twb[n];
        }
        xm[((size_t)b * KCL + k) * CC + t] = s / awf;
    }
}

__global__ __launch_bounds__(256) void k_out(
    const int* __restrict__ idx_token, const float* __restrict__ aggw,
    const float* __restrict__ tw, const float* __restrict__ aw,
    const int* __restrict__ idxc, float* __restrict__ out_idx,
    float* __restrict__ out_agg)
{
    int g = blockIdx.x * 256 + threadIdx.x;
    int b = g >> 11;
    int it = idx_token[g];
    int kclu = idxc[b * NN + it];
    out_idx[g] = (float)kclu;
    float nw = tw[b * NN + it] / aw[b * KCL + kclu];
    out_agg[g] = aggw[g] * nw;
}

extern "C" void kernel_launch(void* const* d_in, const int* in_sizes, int n_in,
                              void* d_out, int out_size, void* d_ws, size_t ws_size,
                              hipStream_t stream) {
    const float* x         = (const float*)d_in[0];
    const int*   idx_token = (const int*)  d_in[1];
    const float* aggw      = (const float*)d_in[2];
    const float* noise     = (const float*)d_in[3];
    const float* sw        = (const float*)d_in[4];
    const float* sb        = (const float*)d_in[5];

    float* ws      = (float*)d_ws;
    float* sq      = ws;                 // B*N
    float* tw      = ws + 32768;         // B*N
    float* dens    = ws + 65536;         // B*N
    float* rowmax  = ws + 98304;         // B*N
    float* score   = ws + 131072;        // B*N
    float* dmax    = ws + 163840;        // 64 slots
    float* aw      = ws + 163904;        // B*512
    int*   idown   = (int*)(ws + 172096);// B*512
    int*   idxc    = (int*)(ws + 180288);// B*N
    int*   invc    = (int*)(ws + 213056);// B*N -> ends 245824

    unsigned short* Xh = (unsigned short*)(ws + 245824);
    unsigned short* Xl = (unsigned short*)(ws + 245824 + 6291456);
    float* Dbuf        = ws + 245824 + 2 * 6291456;

    const size_t head_bytes = (size_t)(245824 + 2 * 6291456) * 4;
    size_t avail = (ws_size > head_bytes) ? (ws_size - head_bytes) : 0;
    int nbg = 0;
    for (int g = 16; g >= 1; g >>= 1) {
        if ((size_t)g * NN * NN * 4 <= avail) { nbg = g; break; }
    }

    float* xm      = (float*)d_out;                      // B*512*C
    float* out_idx = xm + (size_t)BB * KCL * CC;         // B*N
    float* out_agg = out_idx + (size_t)BB * NN;          // B*N

    if (nbg >= 16) {
        // Single full-batch GEMM (max TLP), then the D-consuming tail in
        // REVERSE-write-order groups of 8: batches 8..15 were written last
        // and are L3-resident; reading them first keeps both halves hot.
        k_prep    <<<dim3(BB * NN / 4), 256, 0, stream>>>(x, sw, sb, sq, tw, Xh, Xl);
        k_gemm_sym<<<dim3(136, 1, BB), 256, 0, stream>>>(Xh, Xl, sq, Dbuf, 0);
        for (int gi = 0; gi < 2; ++gi) {
            int b0 = (gi == 0) ? 8 : 0;
            float* Dg = Dbuf + (size_t)b0 * NN * NN;
            k_density2<<<dim3(8 * NN / 4), 256, 0, stream>>>(Dg, noise + b0 * NN,
                                                             dens + b0 * NN, rowmax + b0 * NN);
            k_distmax2<<<dim3(8), 256, 0, stream>>>(rowmax + b0 * NN, dmax + b0);
            k_dmin2   <<<dim3(8 * NN / 4), 256, 0, stream>>>(Dg, dens + b0 * NN,
                                                             dmax + b0, score + b0 * NN);
            k_topk    <<<dim3(8), 1024, 0, stream>>>(score + b0 * NN, idown + b0 * KCL,
                                                     invc + b0 * NN);
            k_assign2 <<<dim3(NN / 64, 8), 256, 0, stream>>>(Dg, idown + b0 * KCL,
                                                             invc + b0 * NN, idxc + b0 * NN);
        }
    } else if (nbg >= 1) {
        k_prep<<<dim3(BB * NN / 4), 256, 0, stream>>>(x, sw, sb, sq, tw, Xh, Xl);
        int G = (nbg >= 8) ? 8 : nbg;
        for (int b0 = 0; b0 < BB; b0 += G) {
            int g = (b0 + G <= BB) ? G : (BB - b0);
            k_gemm_sym<<<dim3(136, 1, g), 256, 0, stream>>>(Xh, Xl, sq, Dbuf, b0);
            k_density2<<<dim3(g * NN / 4), 256, 0, stream>>>(Dbuf, noise + b0 * NN,
                                                             dens + b0 * NN, rowmax + b0 * NN);
            k_distmax2<<<dim3(g), 256, 0, stream>>>(rowmax + b0 * NN, dmax + b0);
            k_dmin2   <<<dim3(g * NN / 4), 256, 0, stream>>>(Dbuf, dens + b0 * NN,
                                                             dmax + b0, score + b0 * NN);
            k_topk    <<<dim3(g), 1024, 0, stream>>>(score + b0 * NN, idown + b0 * KCL,
                                                     invc + b0 * NN);
            k_assign2 <<<dim3(NN / 64, g), 256, 0, stream>>>(Dbuf, idown + b0 * KCL,
                                                             invc + b0 * NN, idxc + b0 * NN);
        }
    } else {
        k_rowstats<<<dim3(BB * NN / 4), 256, 0, stream>>>(x, sw, sb, sq, tw);
        k_density <<<dim3(NN / 64, BB), 256, 0, stream>>>(x, sq, noise, dens, rowmax);
        k_distmax <<<dim3(BB), 256, 0, stream>>>(rowmax, dmax);
        k_dmin    <<<dim3(NN / 64, BB), 256, 0, stream>>>(x, sq, dens, dmax, score);
        k_topk    <<<dim3(BB), 1024, 0, stream>>>(score, idown, invc);
        k_assign  <<<dim3(NN / 64, BB), 256, 0, stream>>>(x, sq, idown, idxc);
        k_override<<<dim3(BB * KCL / 256), 256, 0, stream>>>(idown, idxc);
    }

    k_merge<<<dim3(KCL, BB), 512, 0, stream>>>(x, tw, idxc, aw, xm);
    k_out  <<<dim3(BB * NN / 256), 256, 0, stream>>>(idx_token, aggw, tw, aw, idxc,
                                                     out_idx, out_agg);
}